// Round 2
// baseline (2128.610 us; speedup 1.0000x reference)
//
#include <hip/hip_runtime.h>
#include <hip/hip_bf16.h>

#define BN_EPS 1e-5f

// ---------------------------------------------------------------------------
// Embedding MLP: locs[B*N,2] -> relu(.@W0+b0) -> relu(bn(.@W1+b1)) -> .@Wo+bo
// Block = 256 threads = 4 nodes x 64 threads. Writes x (=d_out buffer).
// ---------------------------------------------------------------------------
__global__ __launch_bounds__(256) void k_embed(
    const float* __restrict__ locs,
    const float* __restrict__ W0, const float* __restrict__ b0,
    const float* __restrict__ W1, const float* __restrict__ b1,
    const float* __restrict__ g1, const float* __restrict__ be1,
    const float* __restrict__ m1, const float* __restrict__ v1,
    const float* __restrict__ Wo, const float* __restrict__ bo,
    float* __restrict__ x) {
  __shared__ float z1[4][64];
  __shared__ float z2[4][64];
  int tid = threadIdx.x;
  int grp = tid >> 6, t = tid & 63;
  int node = blockIdx.x * 4 + grp;           // 16000*4 = 64000 exactly
  float lx = locs[node * 2 + 0], ly = locs[node * 2 + 1];
  float a = fmaxf(fmaf(lx, W0[t], fmaf(ly, W0[64 + t], b0[t])), 0.f);
  z1[grp][t] = a;
  __syncthreads();
  float acc = b1[t];
#pragma unroll
  for (int k = 0; k < 64; ++k) acc = fmaf(z1[grp][k], W1[k * 64 + t], acc);
  float sc = g1[t] * rsqrtf(v1[t] + BN_EPS);
  acc = fmaxf(fmaf(acc - m1[t], sc, be1[t]), 0.f);
  z2[grp][t] = acc;
  __syncthreads();
#pragma unroll
  for (int dd = 0; dd < 2; ++dd) {
    int d = t + dd * 64;
    float o = bo[d];
#pragma unroll
    for (int k = 0; k < 64; ++k) o = fmaf(z2[grp][k], Wo[k * 128 + d], o);
    x[(long)node * 128 + d] = o;
  }
}

// ---------------------------------------------------------------------------
// h = x @ W  (64000x128 @ 128x128), f32. Block: 32 rows, 256 threads,
// each thread owns 16 rows at one column.
// ---------------------------------------------------------------------------
__global__ __launch_bounds__(256) void k_gemm(
    const float* __restrict__ x, const float* __restrict__ W,
    float* __restrict__ h) {
  __shared__ float xs[32][128];
  int tid = threadIdx.x;
  int base = blockIdx.x * 32;
  for (int idx = tid; idx < 32 * 128; idx += 256)
    xs[idx >> 7][idx & 127] = x[(long)base * 128 + idx];
  __syncthreads();
  int d = tid & 127, r0 = (tid >> 7) * 16;
  float acc[16];
#pragma unroll
  for (int r = 0; r < 16; ++r) acc[r] = 0.f;
  for (int k4 = 0; k4 < 32; ++k4) {
    float w0 = W[(k4 * 4 + 0) * 128 + d];
    float w1 = W[(k4 * 4 + 1) * 128 + d];
    float w2 = W[(k4 * 4 + 2) * 128 + d];
    float w3 = W[(k4 * 4 + 3) * 128 + d];
#pragma unroll
    for (int r = 0; r < 16; ++r) {
      float4 xv = *reinterpret_cast<const float4*>(&xs[r0 + r][k4 * 4]);
      acc[r] = fmaf(xv.x, w0, acc[r]);
      acc[r] = fmaf(xv.y, w1, acc[r]);
      acc[r] = fmaf(xv.z, w2, acc[r]);
      acc[r] = fmaf(xv.w, w3, acc[r]);
    }
  }
#pragma unroll
  for (int r = 0; r < 16; ++r)
    h[(long)(base + r0 + r) * 128 + d] = acc[r];
}

// ---------------------------------------------------------------------------
// e_src[n] = h[n,:].a_src ; e_dst[n] = h[n,:].a_dst. 4 nodes/block.
// ---------------------------------------------------------------------------
__global__ __launch_bounds__(256) void k_e(
    const float* __restrict__ h, const float* __restrict__ asrc,
    const float* __restrict__ adst, float* __restrict__ es,
    float* __restrict__ ed) {
  int tid = threadIdx.x;
  int lane = tid & 63;
  int node = blockIdx.x * 4 + (tid >> 6);
  float h0 = h[(long)node * 128 + lane];
  float h1 = h[(long)node * 128 + 64 + lane];
  float ps = fmaf(h0, asrc[lane], h1 * asrc[64 + lane]);
  float pd = fmaf(h0, adst[lane], h1 * adst[64 + lane]);
#pragma unroll
  for (int m = 32; m >= 1; m >>= 1) {
    ps += __shfl_xor(ps, m, 64);
    pd += __shfl_xor(pd, m, 64);
  }
  if (lane == 0) {
    es[node] = ps;
    ed[node] = pd;
  }
}

// ---------------------------------------------------------------------------
// Per-batch sorted two-pointer sweep: exact softmax(leakyrelu(d_i + s_j)) @ h.
// For target i (threshold t_i=-d_i): sources with s_j<=t_i take the 0.2-branch
// exp(0.2(d_i+s_j)), the rest exp(d_i+s_j). Running sums over sorted s give
// both branch partials; emit i when t_i < s_j. One block/batch, 128 threads.
// APPLY_BN: write relu(bn(val)); else raw val (last layer). Output f32.
// ---------------------------------------------------------------------------
template <bool APPLY_BN>
__global__ __launch_bounds__(128) void k_sweep(
    const float* __restrict__ h, const float* __restrict__ es,
    const float* __restrict__ ed, const float* __restrict__ bias,
    const float* __restrict__ bng, const float* __restrict__ bnb,
    const float* __restrict__ bnm, const float* __restrict__ bnv,
    float* __restrict__ xo) {
  __shared__ float ss[1024];
  __shared__ float tt[1024];
  __shared__ int ps[1024];
  __shared__ int pt[1024];
  int tid = threadIdx.x;
  int b = blockIdx.x;
  const float* hb = h + (long)b * 1000 * 128;

  for (int i = tid; i < 1024; i += 128) {
    if (i < 1000) {
      ss[i] = es[b * 1000 + i];
      tt[i] = -ed[b * 1000 + i];
    } else {
      ss[i] = INFINITY;
      tt[i] = INFINITY;
    }
    ps[i] = i;
    pt[i] = i;
  }
  // bitonic sort (ascending) of ss (with ps) and tt (with pt)
  for (int k = 2; k <= 1024; k <<= 1) {
    for (int j = k >> 1; j > 0; j >>= 1) {
      __syncthreads();
      for (int i = tid; i < 1024; i += 128) {
        int ixj = i ^ j;
        if (ixj > i) {
          bool up = ((i & k) == 0);
          float a = ss[i], c = ss[ixj];
          if ((a > c) == up) {
            ss[i] = c; ss[ixj] = a;
            int p = ps[i]; ps[i] = ps[ixj]; ps[ixj] = p;
          }
          float at = tt[i], ct = tt[ixj];
          if ((at > ct) == up) {
            tt[i] = ct; tt[ixj] = at;
            int p = pt[i]; pt[i] = pt[ixj]; pt[ixj] = p;
          }
        }
      }
    }
  }
  __syncthreads();

  int d = tid;  // feature dim
  // totals pre-pass (exp-branch vector total and scalar total)
  float T1 = 0.f, s1tot = 0.f;
  for (int j = 0; j < 1000; ++j) {
    float sj = ss[j];
    float e1 = __expf(sj);
    float hv = hb[(long)ps[j] * 128 + d];
    T1 = fmaf(e1, hv, T1);
    s1tot += e1;
  }

  float bs = bias[d];
  float sc = 0.f, sh = 0.f;
  if (APPLY_BN) {
    float g = bng[d], be = bnb[d], m = bnm[d], v = bnv[d];
    sc = g * rsqrtf(v + BN_EPS);
    sh = be - m * sc;
  }

  // sweep
  float R1 = 0.f, R2 = 0.f, s1 = 0.f, s2 = 0.f;
  int ii = 0;
  for (int j = 0; j <= 1000; ++j) {
    float sj = (j < 1000) ? ss[j] : INFINITY;
    while (ii < 1000 && tt[ii] < sj) {
      float di = -tt[ii];
      float Ed = __expf(di), Ed2 = __expf(0.2f * di);
      float numer = fmaf(Ed, T1 - R1, Ed2 * R2);
      float denom = fmaf(Ed, s1tot - s1, Ed2 * s2);
      float val = numer / denom + bs;
      long off = ((long)b * 1000 + pt[ii]) * 128 + d;
      if (APPLY_BN) {
        xo[off] = fmaxf(fmaf(val, sc, sh), 0.f);
      } else {
        xo[off] = val;
      }
      ++ii;
    }
    if (j < 1000) {
      float e1 = __expf(sj), e2 = __expf(0.2f * sj);
      float hv = hb[(long)ps[j] * 128 + d];
      R1 = fmaf(e1, hv, R1);
      R2 = fmaf(e2, hv, R2);
      s1 += e1;
      s2 += e2;
    }
  }
}

extern "C" void kernel_launch(void* const* d_in, const int* in_sizes, int n_in,
                              void* d_out, int out_size, void* d_ws,
                              size_t ws_size, hipStream_t stream) {
  const float* locs = (const float*)d_in[0];
  const float* le_W0 = (const float*)d_in[1];
  const float* le_b0 = (const float*)d_in[2];
  const float* le_W1 = (const float*)d_in[3];
  const float* le_b1 = (const float*)d_in[4];
  const float* le_bn_g = (const float*)d_in[5];
  const float* le_bn_b = (const float*)d_in[6];
  const float* le_bn_m = (const float*)d_in[7];
  const float* le_bn_v = (const float*)d_in[8];
  const float* le_Wo = (const float*)d_in[9];
  const float* le_bo = (const float*)d_in[10];
  const float* gat_W = (const float*)d_in[11];
  const float* gat_asrc = (const float*)d_in[12];
  const float* gat_adst = (const float*)d_in[13];
  const float* gat_b = (const float*)d_in[14];
  const float* bn_g = (const float*)d_in[15];
  const float* bn_b = (const float*)d_in[16];
  const float* bn_m = (const float*)d_in[17];
  const float* bn_v = (const float*)d_in[18];

  // x lives in d_out (8,192,000 f32 exactly); h + es/ed in ws (33.3 MB).
  float* x = (float*)d_out;
  float* h = (float*)d_ws;              // 8,192,000 f32
  float* es = h + 8192000;              // 64,000 f32
  float* ed = es + 64000;               // 64,000 f32

  k_embed<<<16000, 256, 0, stream>>>(locs, le_W0, le_b0, le_W1, le_b1, le_bn_g,
                                     le_bn_b, le_bn_m, le_bn_v, le_Wo, le_bo,
                                     x);
  for (int l = 0; l < 3; ++l) {
    k_gemm<<<2000, 256, 0, stream>>>(x, gat_W + l * 128 * 128, h);
    k_e<<<16000, 256, 0, stream>>>(h, gat_asrc + l * 128, gat_adst + l * 128,
                                   es, ed);
    if (l < 2) {
      k_sweep<true><<<64, 128, 0, stream>>>(
          h, es, ed, gat_b + l * 128, bn_g + l * 128, bn_b + l * 128,
          bn_m + l * 128, bn_v + l * 128, x);
    } else {
      // Final layer: no BN/ReLU; writes the network output into d_out (=x).
      // No race: reads h (ws) + es/ed only, never x.
      k_sweep<false><<<64, 128, 0, stream>>>(h, es, ed, gat_b + 2 * 128,
                                             nullptr, nullptr, nullptr,
                                             nullptr, x);
    }
  }
}

// Round 4
// 482.681 us; speedup vs baseline: 4.4100x; 4.4100x over previous
//
#include <hip/hip_runtime.h>
#include <hip/hip_bf16.h>

#define BN_EPS 1e-5f
#define NB 64
#define NN 1000
#define NP 1024
#define HD 128
#define CS 8
#define NC 125  // NN/CS exactly

// ---------------------------------------------------------------------------
// Embedding MLP: locs[B*N,2] -> relu(.@W0+b0) -> relu(bn(.@W1+b1)) -> .@Wo+bo
// ---------------------------------------------------------------------------
__global__ __launch_bounds__(256) void k_embed(
    const float* __restrict__ locs,
    const float* __restrict__ W0, const float* __restrict__ b0,
    const float* __restrict__ W1, const float* __restrict__ b1,
    const float* __restrict__ g1, const float* __restrict__ be1,
    const float* __restrict__ m1, const float* __restrict__ v1,
    const float* __restrict__ Wo, const float* __restrict__ bo,
    float* __restrict__ x) {
  __shared__ float z1[4][64];
  __shared__ float z2[4][64];
  int tid = threadIdx.x;
  int grp = tid >> 6, t = tid & 63;
  int node = blockIdx.x * 4 + grp;
  float lx = locs[node * 2 + 0], ly = locs[node * 2 + 1];
  float a = fmaxf(fmaf(lx, W0[t], fmaf(ly, W0[64 + t], b0[t])), 0.f);
  z1[grp][t] = a;
  __syncthreads();
  float acc = b1[t];
#pragma unroll
  for (int k = 0; k < 64; ++k) acc = fmaf(z1[grp][k], W1[k * 64 + t], acc);
  float sc = g1[t] * rsqrtf(v1[t] + BN_EPS);
  acc = fmaxf(fmaf(acc - m1[t], sc, be1[t]), 0.f);
  z2[grp][t] = acc;
  __syncthreads();
#pragma unroll
  for (int dd = 0; dd < 2; ++dd) {
    int d = t + dd * 64;
    float o = bo[d];
#pragma unroll
    for (int k = 0; k < 64; ++k) o = fmaf(z2[grp][k], Wo[k * 128 + d], o);
    x[(long)node * 128 + d] = o;
  }
}

// ---------------------------------------------------------------------------
// h = x @ W  (64000x128 @ 128x128), f32.
// ---------------------------------------------------------------------------
__global__ __launch_bounds__(256) void k_gemm(
    const float* __restrict__ x, const float* __restrict__ W,
    float* __restrict__ h) {
  __shared__ float xs[32][128];
  int tid = threadIdx.x;
  int base = blockIdx.x * 32;
  for (int idx = tid; idx < 32 * 128; idx += 256)
    xs[idx >> 7][idx & 127] = x[(long)base * 128 + idx];
  __syncthreads();
  int d = tid & 127, r0 = (tid >> 7) * 16;
  float acc[16];
#pragma unroll
  for (int r = 0; r < 16; ++r) acc[r] = 0.f;
  for (int k4 = 0; k4 < 32; ++k4) {
    float w0 = W[(k4 * 4 + 0) * 128 + d];
    float w1 = W[(k4 * 4 + 1) * 128 + d];
    float w2 = W[(k4 * 4 + 2) * 128 + d];
    float w3 = W[(k4 * 4 + 3) * 128 + d];
#pragma unroll
    for (int r = 0; r < 16; ++r) {
      float4 xv = *reinterpret_cast<const float4*>(&xs[r0 + r][k4 * 4]);
      acc[r] = fmaf(xv.x, w0, acc[r]);
      acc[r] = fmaf(xv.y, w1, acc[r]);
      acc[r] = fmaf(xv.z, w2, acc[r]);
      acc[r] = fmaf(xv.w, w3, acc[r]);
    }
  }
#pragma unroll
  for (int r = 0; r < 16; ++r)
    h[(long)(base + r0 + r) * 128 + d] = acc[r];
}

// ---------------------------------------------------------------------------
// e_src[n] = h[n,:].a_src ; e_dst[n] = h[n,:].a_dst
// ---------------------------------------------------------------------------
__global__ __launch_bounds__(256) void k_e(
    const float* __restrict__ h, const float* __restrict__ asrc,
    const float* __restrict__ adst, float* __restrict__ es,
    float* __restrict__ ed) {
  int tid = threadIdx.x;
  int lane = tid & 63;
  int node = blockIdx.x * 4 + (tid >> 6);
  float h0 = h[(long)node * 128 + lane];
  float h1 = h[(long)node * 128 + 64 + lane];
  float ps = fmaf(h0, asrc[lane], h1 * asrc[64 + lane]);
  float pd = fmaf(h0, adst[lane], h1 * adst[64 + lane]);
#pragma unroll
  for (int m = 32; m >= 1; m >>= 1) {
    ps += __shfl_xor(ps, m, 64);
    pd += __shfl_xor(pd, m, 64);
  }
  if (lane == 0) {
    es[node] = ps;
    ed[node] = pd;
  }
}

// ---------------------------------------------------------------------------
// Per batch: sort s (asc, with perm), scalar e1/e2 prefix scan, then per
// target: k_i = upper_bound(t_i), denom, alpha/beta coefficients.
// ---------------------------------------------------------------------------
__global__ __launch_bounds__(256) void k_sort(
    const float* __restrict__ es, const float* __restrict__ ed,
    float* __restrict__ e1s, float* __restrict__ e2s, int* __restrict__ perm,
    int* __restrict__ kcut, float* __restrict__ alpha,
    float* __restrict__ beta) {
  __shared__ float ss[NP];
  __shared__ int id[NP];
  __shared__ float2 sa[NP];
  __shared__ float2 sb[NP];
  int tid = threadIdx.x, b = blockIdx.x;
  for (int i = tid; i < NP; i += 256) {
    ss[i] = (i < NN) ? es[b * NN + i] : INFINITY;
    id[i] = i;
  }
  // bitonic sort ascending
  for (int k = 2; k <= NP; k <<= 1) {
    for (int j = k >> 1; j > 0; j >>= 1) {
      __syncthreads();
      for (int i = tid; i < NP; i += 256) {
        int ixj = i ^ j;
        if (ixj > i) {
          bool up = ((i & k) == 0);
          float a = ss[i], c = ss[ixj];
          if ((a > c) == up) {
            ss[i] = c; ss[ixj] = a;
            int p = id[i]; id[i] = id[ixj]; id[ixj] = p;
          }
        }
      }
    }
  }
  __syncthreads();
  // exp values; persist (pre-scan) to global; seed scan buffer
  for (int i = tid; i < NP; i += 256) {
    float e1 = 0.f, e2 = 0.f;
    if (i < NN) {
      float s = ss[i];
      e1 = __expf(s);
      e2 = __expf(0.2f * s);
      e1s[b * NN + i] = e1;
      e2s[b * NN + i] = e2;
      perm[b * NN + i] = id[i];
    }
    sa[i] = make_float2(e1, e2);
  }
  __syncthreads();
  // Hillis-Steele inclusive scan (double-buffered), 10 passes
  float2* src = sa;
  float2* dst = sb;
  for (int off = 1; off < NP; off <<= 1) {
    for (int i = tid; i < NP; i += 256) {
      float2 v = src[i];
      if (i >= off) {
        float2 u = src[i - off];
        v.x += u.x;
        v.y += u.y;
      }
      dst[i] = v;
    }
    __syncthreads();
    float2* t = src; src = dst; dst = t;
  }
  float s1tot = src[NN - 1].x;
  // per-target coefficients
  for (int i = tid; i < NN; i += 256) {
    float t = -ed[b * NN + i];
    int lo = 0, hi = NP;
    while (lo < hi) {
      int mid = (lo + hi) >> 1;
      if (ss[mid] <= t) lo = mid + 1; else hi = mid;
    }
    int k = lo;  // #{s_j <= t_i}, <= NN since pads are +INF
    float p1 = (k > 0) ? src[k - 1].x : 0.f;
    float p2 = (k > 0) ? src[k - 1].y : 0.f;
    float Ed = __expf(-t);
    float Ed2 = __expf(-0.2f * t);
    float den = fmaf(Ed, s1tot - p1, Ed2 * p2);
    kcut[b * NN + i] = k;
    alpha[b * NN + i] = Ed / den;
    beta[b * NN + i] = Ed2 / den;
  }
}

// ---------------------------------------------------------------------------
// Per-chunk (8 sorted sources) weighted sums V1/V2 over dims.
// grid (B, 8): block g handles chunks [g*16, min(g*16+16,NC)).
// ---------------------------------------------------------------------------
__global__ __launch_bounds__(128) void k_chunk(
    const float* __restrict__ h, const float* __restrict__ e1s,
    const float* __restrict__ e2s, const int* __restrict__ perm,
    float* __restrict__ C1, float* __restrict__ C2) {
  int d = threadIdx.x, b = blockIdx.x, g = blockIdx.y;
  int c0 = g * 16, c1 = min(c0 + 16, NC);
  for (int c = c0; c < c1; ++c) {
    float v1 = 0.f, v2 = 0.f;
#pragma unroll
    for (int u = 0; u < CS; ++u) {
      int j = c * CS + u;
      int p = perm[b * NN + j];
      float hv = h[((long)b * NN + p) * HD + d];
      v1 = fmaf(e1s[b * NN + j], hv, v1);
      v2 = fmaf(e2s[b * NN + j], hv, v2);
    }
    C1[((long)b * (NC + 1) + c) * HD + d] = v1;
    C2[((long)b * (NC + 1) + c) * HD + d] = v2;
  }
}

// ---------------------------------------------------------------------------
// In-place exclusive prefix over chunks; slot NC receives totals.
// ---------------------------------------------------------------------------
__global__ __launch_bounds__(128) void k_cprefix(float* __restrict__ C1,
                                                 float* __restrict__ C2) {
  int d = threadIdx.x, b = blockIdx.x;
  float r1 = 0.f, r2 = 0.f;
  for (int c = 0; c < NC; ++c) {
    long o = ((long)b * (NC + 1) + c) * HD + d;
    float v1 = C1[o], v2 = C2[o];
    C1[o] = r1;
    C2[o] = r2;
    r1 += v1;
    r2 += v2;
  }
  long o = ((long)b * (NC + 1) + NC) * HD + d;
  C1[o] = r1;
  C2[o] = r2;
}

// ---------------------------------------------------------------------------
// out[i] = alpha_i*(T1 - C1[c_i] - partial1) + beta_i*(C2[c_i] + partial2)
//          + bias  (then optional BN+ReLU). grid (B, NC=125): 8 targets/block.
// ---------------------------------------------------------------------------
template <bool APPLY_BN>
__global__ __launch_bounds__(128) void k_out(
    const float* __restrict__ h, const float* __restrict__ C1,
    const float* __restrict__ C2, const float* __restrict__ e1s,
    const float* __restrict__ e2s, const int* __restrict__ perm,
    const int* __restrict__ kcut, const float* __restrict__ alpha,
    const float* __restrict__ beta, const float* __restrict__ bias,
    const float* __restrict__ bng, const float* __restrict__ bnb,
    const float* __restrict__ bnm, const float* __restrict__ bnv,
    float* __restrict__ xo) {
  int d = threadIdx.x, b = blockIdx.x;
  int i0 = blockIdx.y * 8;
  float T1 = C1[((long)b * (NC + 1) + NC) * HD + d];
  float bs = bias[d];
  float sc = 0.f, sh = 0.f;
  if (APPLY_BN) {
    float g = bng[d], bb = bnb[d], m = bnm[d], v = bnv[d];
    sc = g * rsqrtf(v + BN_EPS);
    sh = bb - m * sc;
  }
  for (int i = i0; i < i0 + 8; ++i) {
    int k = kcut[b * NN + i];
    float al = alpha[b * NN + i], bt = beta[b * NN + i];
    int c = k >> 3;  // chunk index, <= NC
    float base1 = C1[((long)b * (NC + 1) + c) * HD + d];
    float base2 = C2[((long)b * (NC + 1) + c) * HD + d];
    float p1 = 0.f, p2 = 0.f;
    for (int j = c * CS; j < k; ++j) {
      int p = perm[b * NN + j];
      float hv = h[((long)b * NN + p) * HD + d];
      p1 = fmaf(e1s[b * NN + j], hv, p1);
      p2 = fmaf(e2s[b * NN + j], hv, p2);
    }
    float val = fmaf(al, T1 - base1 - p1, fmaf(bt, base2 + p2, bs));
    long off = ((long)b * NN + i) * HD + d;
    xo[off] = APPLY_BN ? fmaxf(fmaf(val, sc, sh), 0.f) : val;
  }
}

extern "C" void kernel_launch(void* const* d_in, const int* in_sizes, int n_in,
                              void* d_out, int out_size, void* d_ws,
                              size_t ws_size, hipStream_t stream) {
  const float* locs = (const float*)d_in[0];
  const float* le_W0 = (const float*)d_in[1];
  const float* le_b0 = (const float*)d_in[2];
  const float* le_W1 = (const float*)d_in[3];
  const float* le_b1 = (const float*)d_in[4];
  const float* le_bn_g = (const float*)d_in[5];
  const float* le_bn_b = (const float*)d_in[6];
  const float* le_bn_m = (const float*)d_in[7];
  const float* le_bn_v = (const float*)d_in[8];
  const float* le_Wo = (const float*)d_in[9];
  const float* le_bo = (const float*)d_in[10];
  const float* gat_W = (const float*)d_in[11];
  const float* gat_asrc = (const float*)d_in[12];
  const float* gat_adst = (const float*)d_in[13];
  const float* gat_b = (const float*)d_in[14];
  const float* bn_g = (const float*)d_in[15];
  const float* bn_b = (const float*)d_in[16];
  const float* bn_m = (const float*)d_in[17];
  const float* bn_v = (const float*)d_in[18];

  // x lives in d_out (8,192,000 f32 exactly). ws: ~43 MB.
  float* x = (float*)d_out;
  float* h = (float*)d_ws;                 // 8,192,000
  float* C1 = h + 8192000;                 // 64*126*128 = 1,032,192
  float* C2 = C1 + 1032192;                // 1,032,192
  float* es = C2 + 1032192;                // 64,000
  float* ed = es + 64000;
  float* e1s = ed + 64000;
  float* e2s = e1s + 64000;
  float* alpha = e2s + 64000;
  float* beta = alpha + 64000;
  int* perm = (int*)(beta + 64000);
  int* kcut = perm + 64000;

  k_embed<<<16000, 256, 0, stream>>>(locs, le_W0, le_b0, le_W1, le_b1, le_bn_g,
                                     le_bn_b, le_bn_m, le_bn_v, le_Wo, le_bo,
                                     x);
  for (int l = 0; l < 3; ++l) {
    k_gemm<<<2000, 256, 0, stream>>>(x, gat_W + l * 128 * 128, h);
    k_e<<<16000, 256, 0, stream>>>(h, gat_asrc + l * 128, gat_adst + l * 128,
                                   es, ed);
    k_sort<<<NB, 256, 0, stream>>>(es, ed, e1s, e2s, perm, kcut, alpha, beta);
    k_chunk<<<dim3(NB, 8), 128, 0, stream>>>(h, e1s, e2s, perm, C1, C2);
    k_cprefix<<<NB, 128, 0, stream>>>(C1, C2);
    if (l < 2) {
      k_out<true><<<dim3(NB, NC), 128, 0, stream>>>(
          h, C1, C2, e1s, e2s, perm, kcut, alpha, beta, gat_b + l * 128,
          bn_g + l * 128, bn_b + l * 128, bn_m + l * 128, bn_v + l * 128, x);
    } else {
      k_out<false><<<dim3(NB, NC), 128, 0, stream>>>(
          h, C1, C2, e1s, e2s, perm, kcut, alpha, beta, gat_b + 2 * 128,
          nullptr, nullptr, nullptr, nullptr, x);
    }
  }
}

// Round 5
// 378.601 us; speedup vs baseline: 5.6223x; 1.2749x over previous
//
#include <hip/hip_runtime.h>
#include <hip/hip_bf16.h>

#define BN_EPS 1e-5f
#define NB 64
#define NN 1000
#define NP 1024
#define HD 128
#define CS 8
#define NC 125  // NN/CS exactly

// ---------------------------------------------------------------------------
// Embedding MLP, register-tiled. 64 nodes/block, 256 threads.
// Phase A: z1=relu(locs@W0+b0) -> z1T[d][n] (LDS, transposed)
// Phase B: z2=relu(bn(z1@W1+b1)) -> z2T[d][n]
// Phase C: x = z2@Wo + bo (coalesced stores)
// Thread tile: 4 nodes (nt=tid&15) x 4 dims (dt=tid>>4); weights come from
// L1 as wave-shared 64B lines; each load feeds 16/32 FMAs.
// ---------------------------------------------------------------------------
__global__ __launch_bounds__(256) void k_embed(
    const float* __restrict__ locs,
    const float* __restrict__ W0, const float* __restrict__ b0,
    const float* __restrict__ W1, const float* __restrict__ b1,
    const float* __restrict__ g1, const float* __restrict__ be1,
    const float* __restrict__ m1, const float* __restrict__ v1,
    const float* __restrict__ Wo, const float* __restrict__ bo,
    float* __restrict__ x) {
  __shared__ float z1T[64][68];
  __shared__ float z2T[64][68];
  int tid = threadIdx.x;
  long base = (long)blockIdx.x * 64;

  // ---- phase A ----
  {
    int d = tid & 63;
    int q = tid >> 6;  // wave id 0..3
    float w0x = W0[d], w0y = W0[64 + d], bb = b0[d];
#pragma unroll
    for (int g = 0; g < 4; ++g) {
      float vv[4];
#pragma unroll
      for (int i = 0; i < 4; ++i) {
        int n = g * 16 + q * 4 + i;
        float lx = locs[(base + n) * 2 + 0];
        float ly = locs[(base + n) * 2 + 1];
        vv[i] = fmaxf(fmaf(lx, w0x, fmaf(ly, w0y, bb)), 0.f);
      }
      float4 v = make_float4(vv[0], vv[1], vv[2], vv[3]);
      *(float4*)&z1T[d][g * 16 + q * 4] = v;
    }
  }
  __syncthreads();

  int nt = tid & 15;   // nodes 4nt..4nt+3
  int dt = tid >> 4;   // dims 4dt..4dt+3 (and +64 in phase C)

  // ---- phase B ----
  {
    float acc[4][4];
#pragma unroll
    for (int i = 0; i < 4; ++i)
#pragma unroll
      for (int j = 0; j < 4; ++j) acc[i][j] = 0.f;
#pragma unroll 4
    for (int k = 0; k < 64; ++k) {
      float4 zv = *(const float4*)&z1T[k][4 * nt];
      float4 wv = *(const float4*)&W1[k * 64 + 4 * dt];
      float zz[4] = {zv.x, zv.y, zv.z, zv.w};
      float ww[4] = {wv.x, wv.y, wv.z, wv.w};
#pragma unroll
      for (int i = 0; i < 4; ++i)
#pragma unroll
        for (int j = 0; j < 4; ++j)
          acc[i][j] = fmaf(zz[i], ww[j], acc[i][j]);
    }
    float4 b1v = *(const float4*)&b1[4 * dt];
    float4 g1v = *(const float4*)&g1[4 * dt];
    float4 bev = *(const float4*)&be1[4 * dt];
    float4 m1v = *(const float4*)&m1[4 * dt];
    float4 v1v = *(const float4*)&v1[4 * dt];
    float bbv[4] = {b1v.x, b1v.y, b1v.z, b1v.w};
    float ggv[4] = {g1v.x, g1v.y, g1v.z, g1v.w};
    float eev[4] = {bev.x, bev.y, bev.z, bev.w};
    float mmv[4] = {m1v.x, m1v.y, m1v.z, m1v.w};
    float vvv[4] = {v1v.x, v1v.y, v1v.z, v1v.w};
#pragma unroll
    for (int j = 0; j < 4; ++j) {
      float sc = ggv[j] * rsqrtf(vvv[j] + BN_EPS);
      float sh = eev[j] - mmv[j] * sc;
      float o[4];
#pragma unroll
      for (int i = 0; i < 4; ++i)
        o[i] = fmaxf(fmaf(acc[i][j] + bbv[j], sc, sh), 0.f);
      *(float4*)&z2T[4 * dt + j][4 * nt] = make_float4(o[0], o[1], o[2], o[3]);
    }
  }
  __syncthreads();

  // ---- phase C ----
  {
    float acc[4][8];
#pragma unroll
    for (int i = 0; i < 4; ++i)
#pragma unroll
      for (int j = 0; j < 8; ++j) acc[i][j] = 0.f;
#pragma unroll 2
    for (int k = 0; k < 64; ++k) {
      float4 zv = *(const float4*)&z2T[k][4 * nt];
      float4 wa = *(const float4*)&Wo[k * 128 + 4 * dt];
      float4 wb = *(const float4*)&Wo[k * 128 + 64 + 4 * dt];
      float zz[4] = {zv.x, zv.y, zv.z, zv.w};
      float w0[4] = {wa.x, wa.y, wa.z, wa.w};
      float w1[4] = {wb.x, wb.y, wb.z, wb.w};
#pragma unroll
      for (int i = 0; i < 4; ++i) {
#pragma unroll
        for (int j = 0; j < 4; ++j) {
          acc[i][j] = fmaf(zz[i], w0[j], acc[i][j]);
          acc[i][4 + j] = fmaf(zz[i], w1[j], acc[i][4 + j]);
        }
      }
    }
    float4 bo0 = *(const float4*)&bo[4 * dt];
    float4 bo1 = *(const float4*)&bo[64 + 4 * dt];
#pragma unroll
    for (int i = 0; i < 4; ++i) {
      float4 o0 = make_float4(acc[i][0] + bo0.x, acc[i][1] + bo0.y,
                              acc[i][2] + bo0.z, acc[i][3] + bo0.w);
      float4 o1 = make_float4(acc[i][4] + bo1.x, acc[i][5] + bo1.y,
                              acc[i][6] + bo1.z, acc[i][7] + bo1.w);
      *(float4*)&x[(base + 4 * nt + i) * 128 + 4 * dt] = o0;
      *(float4*)&x[(base + 4 * nt + i) * 128 + 64 + 4 * dt] = o1;
    }
  }
}

// ---------------------------------------------------------------------------
// h = x @ W (64 rows/block, register-tiled 4x8) fused with
// e_src/e_dst row dots (shuffle + LDS cross-wave reduction).
// ---------------------------------------------------------------------------
__global__ __launch_bounds__(256) void k_gemm_e(
    const float* __restrict__ x, const float* __restrict__ W,
    const float* __restrict__ asrc, const float* __restrict__ adst,
    float* __restrict__ h, float* __restrict__ es, float* __restrict__ ed) {
  __shared__ float xs[64][130];
  __shared__ float red[4][64][2];
  int tid = threadIdx.x;
  long base = (long)blockIdx.x * 64;

  // stage x tile (row-major, pad 130; b64 writes ~4-way)
#pragma unroll
  for (int p = 0; p < 8; ++p) {
    int idx = p * 1024 + tid * 4;
    int row = idx >> 7, col = idx & 127;
    float4 v = *(const float4*)&x[(base + row) * 128 + col];
    *(float2*)&xs[row][col] = make_float2(v.x, v.y);
    *(float2*)&xs[row][col + 2] = make_float2(v.z, v.w);
  }
  __syncthreads();

  int nt = tid & 15, dt = tid >> 4;
  float acc[4][8];
#pragma unroll
  for (int i = 0; i < 4; ++i)
#pragma unroll
    for (int j = 0; j < 8; ++j) acc[i][j] = 0.f;

#pragma unroll 4
  for (int k = 0; k < 128; ++k) {
    float4 wa = *(const float4*)&W[k * 128 + 4 * dt];
    float4 wb = *(const float4*)&W[k * 128 + 64 + 4 * dt];
    float w0[4] = {wa.x, wa.y, wa.z, wa.w};
    float w1[4] = {wb.x, wb.y, wb.z, wb.w};
    float zz[4];
#pragma unroll
    for (int i = 0; i < 4; ++i) zz[i] = xs[4 * nt + i][k];
#pragma unroll
    for (int i = 0; i < 4; ++i) {
#pragma unroll
      for (int j = 0; j < 4; ++j) {
        acc[i][j] = fmaf(zz[i], w0[j], acc[i][j]);
        acc[i][4 + j] = fmaf(zz[i], w1[j], acc[i][4 + j]);
      }
    }
  }

  // epilogue: store h, per-row e partials
  float4 as0 = *(const float4*)&asrc[4 * dt];
  float4 as1 = *(const float4*)&asrc[64 + 4 * dt];
  float4 ad0 = *(const float4*)&adst[4 * dt];
  float4 ad1 = *(const float4*)&adst[64 + 4 * dt];
  float ps[4], pd[4];
#pragma unroll
  for (int i = 0; i < 4; ++i) {
    float4 o0 = make_float4(acc[i][0], acc[i][1], acc[i][2], acc[i][3]);
    float4 o1 = make_float4(acc[i][4], acc[i][5], acc[i][6], acc[i][7]);
    *(float4*)&h[(base + 4 * nt + i) * 128 + 4 * dt] = o0;
    *(float4*)&h[(base + 4 * nt + i) * 128 + 64 + 4 * dt] = o1;
    ps[i] = o0.x * as0.x + o0.y * as0.y + o0.z * as0.z + o0.w * as0.w +
            o1.x * as1.x + o1.y * as1.y + o1.z * as1.z + o1.w * as1.w;
    pd[i] = o0.x * ad0.x + o0.y * ad0.y + o0.z * ad0.z + o0.w * ad0.w +
            o1.x * ad1.x + o1.y * ad1.y + o1.z * ad1.z + o1.w * ad1.w;
  }
  // reduce over the wave's 4 dt groups (lanes nt, nt+16, nt+32, nt+48)
#pragma unroll
  for (int i = 0; i < 4; ++i) {
    ps[i] += __shfl_xor(ps[i], 16, 64);
    ps[i] += __shfl_xor(ps[i], 32, 64);
    pd[i] += __shfl_xor(pd[i], 16, 64);
    pd[i] += __shfl_xor(pd[i], 32, 64);
  }
  int w = tid >> 6, lane = tid & 63;
  if (lane < 16) {
#pragma unroll
    for (int i = 0; i < 4; ++i) {
      red[w][4 * lane + i][0] = ps[i];
      red[w][4 * lane + i][1] = pd[i];
    }
  }
  __syncthreads();
  if (tid < 64) {
    float s = red[0][tid][0] + red[1][tid][0] + red[2][tid][0] + red[3][tid][0];
    float dd = red[0][tid][1] + red[1][tid][1] + red[2][tid][1] + red[3][tid][1];
    es[base + tid] = s;
    ed[base + tid] = dd;
  }
}

// ---------------------------------------------------------------------------
// Per batch: sort s (asc, with perm), e1/e2 prefix scan, per-target coeffs.
// ---------------------------------------------------------------------------
__global__ __launch_bounds__(256) void k_sort(
    const float* __restrict__ es, const float* __restrict__ ed,
    float* __restrict__ e1s, float* __restrict__ e2s, int* __restrict__ perm,
    int* __restrict__ kcut, float* __restrict__ alpha,
    float* __restrict__ beta) {
  __shared__ float ss[NP];
  __shared__ int id[NP];
  __shared__ float2 sa[NP];
  __shared__ float2 sb[NP];
  int tid = threadIdx.x, b = blockIdx.x;
  for (int i = tid; i < NP; i += 256) {
    ss[i] = (i < NN) ? es[b * NN + i] : INFINITY;
    id[i] = i;
  }
  for (int k = 2; k <= NP; k <<= 1) {
    for (int j = k >> 1; j > 0; j >>= 1) {
      __syncthreads();
      for (int i = tid; i < NP; i += 256) {
        int ixj = i ^ j;
        if (ixj > i) {
          bool up = ((i & k) == 0);
          float a = ss[i], c = ss[ixj];
          if ((a > c) == up) {
            ss[i] = c; ss[ixj] = a;
            int p = id[i]; id[i] = id[ixj]; id[ixj] = p;
          }
        }
      }
    }
  }
  __syncthreads();
  for (int i = tid; i < NP; i += 256) {
    float e1 = 0.f, e2 = 0.f;
    if (i < NN) {
      float s = ss[i];
      e1 = __expf(s);
      e2 = __expf(0.2f * s);
      e1s[b * NN + i] = e1;
      e2s[b * NN + i] = e2;
      perm[b * NN + i] = id[i];
    }
    sa[i] = make_float2(e1, e2);
  }
  __syncthreads();
  float2* src = sa;
  float2* dst = sb;
  for (int off = 1; off < NP; off <<= 1) {
    for (int i = tid; i < NP; i += 256) {
      float2 v = src[i];
      if (i >= off) {
        float2 u = src[i - off];
        v.x += u.x;
        v.y += u.y;
      }
      dst[i] = v;
    }
    __syncthreads();
    float2* t = src; src = dst; dst = t;
  }
  float s1tot = src[NN - 1].x;
  for (int i = tid; i < NN; i += 256) {
    float t = -ed[b * NN + i];
    int lo = 0, hi = NP;
    while (lo < hi) {
      int mid = (lo + hi) >> 1;
      if (ss[mid] <= t) lo = mid + 1; else hi = mid;
    }
    int k = lo;
    float p1 = (k > 0) ? src[k - 1].x : 0.f;
    float p2 = (k > 0) ? src[k - 1].y : 0.f;
    float Ed = __expf(-t);
    float Ed2 = __expf(-0.2f * t);
    float den = fmaf(Ed, s1tot - p1, Ed2 * p2);
    kcut[b * NN + i] = k;
    alpha[b * NN + i] = Ed / den;
    beta[b * NN + i] = Ed2 / den;
  }
}

// ---------------------------------------------------------------------------
// Per-chunk (8 sorted sources) weighted sums V1/V2 over dims.
// ---------------------------------------------------------------------------
__global__ __launch_bounds__(128) void k_chunk(
    const float* __restrict__ h, const float* __restrict__ e1s,
    const float* __restrict__ e2s, const int* __restrict__ perm,
    float* __restrict__ C1, float* __restrict__ C2) {
  int d = threadIdx.x, b = blockIdx.x, g = blockIdx.y;
  int c0 = g * 16, c1 = min(c0 + 16, NC);
  for (int c = c0; c < c1; ++c) {
    float v1 = 0.f, v2 = 0.f;
#pragma unroll
    for (int u = 0; u < CS; ++u) {
      int j = c * CS + u;
      int p = perm[b * NN + j];
      float hv = h[((long)b * NN + p) * HD + d];
      v1 = fmaf(e1s[b * NN + j], hv, v1);
      v2 = fmaf(e2s[b * NN + j], hv, v2);
    }
    C1[((long)b * (NC + 1) + c) * HD + d] = v1;
    C2[((long)b * (NC + 1) + c) * HD + d] = v2;
  }
}

// ---------------------------------------------------------------------------
// In-place exclusive prefix over chunks; slot NC receives totals.
// ---------------------------------------------------------------------------
__global__ __launch_bounds__(128) void k_cprefix(float* __restrict__ C1,
                                                 float* __restrict__ C2) {
  int d = threadIdx.x, b = blockIdx.x;
  float r1 = 0.f, r2 = 0.f;
  for (int c = 0; c < NC; ++c) {
    long o = ((long)b * (NC + 1) + c) * HD + d;
    float v1 = C1[o], v2 = C2[o];
    C1[o] = r1;
    C2[o] = r2;
    r1 += v1;
    r2 += v2;
  }
  long o = ((long)b * (NC + 1) + NC) * HD + d;
  C1[o] = r1;
  C2[o] = r2;
}

// ---------------------------------------------------------------------------
// out[i] = alpha_i*(T1 - C1[c_i] - partial1) + beta_i*(C2[c_i] + partial2)
// ---------------------------------------------------------------------------
template <bool APPLY_BN>
__global__ __launch_bounds__(128) void k_out(
    const float* __restrict__ h, const float* __restrict__ C1,
    const float* __restrict__ C2, const float* __restrict__ e1s,
    const float* __restrict__ e2s, const int* __restrict__ perm,
    const int* __restrict__ kcut, const float* __restrict__ alpha,
    const float* __restrict__ beta, const float* __restrict__ bias,
    const float* __restrict__ bng, const float* __restrict__ bnb,
    const float* __restrict__ bnm, const float* __restrict__ bnv,
    float* __restrict__ xo) {
  int d = threadIdx.x, b = blockIdx.x;
  int i0 = blockIdx.y * 8;
  float T1 = C1[((long)b * (NC + 1) + NC) * HD + d];
  float bs = bias[d];
  float sc = 0.f, sh = 0.f;
  if (APPLY_BN) {
    float g = bng[d], bb = bnb[d], m = bnm[d], v = bnv[d];
    sc = g * rsqrtf(v + BN_EPS);
    sh = bb - m * sc;
  }
  for (int i = i0; i < i0 + 8; ++i) {
    int k = kcut[b * NN + i];
    float al = alpha[b * NN + i], bt = beta[b * NN + i];
    int c = k >> 3;
    float base1 = C1[((long)b * (NC + 1) + c) * HD + d];
    float base2 = C2[((long)b * (NC + 1) + c) * HD + d];
    float p1 = 0.f, p2 = 0.f;
    for (int j = c * CS; j < k; ++j) {
      int p = perm[b * NN + j];
      float hv = h[((long)b * NN + p) * HD + d];
      p1 = fmaf(e1s[b * NN + j], hv, p1);
      p2 = fmaf(e2s[b * NN + j], hv, p2);
    }
    float val = fmaf(al, T1 - base1 - p1, fmaf(bt, base2 + p2, bs));
    long off = ((long)b * NN + i) * HD + d;
    xo[off] = APPLY_BN ? fmaxf(fmaf(val, sc, sh), 0.f) : val;
  }
}

extern "C" void kernel_launch(void* const* d_in, const int* in_sizes, int n_in,
                              void* d_out, int out_size, void* d_ws,
                              size_t ws_size, hipStream_t stream) {
  const float* locs = (const float*)d_in[0];
  const float* le_W0 = (const float*)d_in[1];
  const float* le_b0 = (const float*)d_in[2];
  const float* le_W1 = (const float*)d_in[3];
  const float* le_b1 = (const float*)d_in[4];
  const float* le_bn_g = (const float*)d_in[5];
  const float* le_bn_b = (const float*)d_in[6];
  const float* le_bn_m = (const float*)d_in[7];
  const float* le_bn_v = (const float*)d_in[8];
  const float* le_Wo = (const float*)d_in[9];
  const float* le_bo = (const float*)d_in[10];
  const float* gat_W = (const float*)d_in[11];
  const float* gat_asrc = (const float*)d_in[12];
  const float* gat_adst = (const float*)d_in[13];
  const float* gat_b = (const float*)d_in[14];
  const float* bn_g = (const float*)d_in[15];
  const float* bn_b = (const float*)d_in[16];
  const float* bn_m = (const float*)d_in[17];
  const float* bn_v = (const float*)d_in[18];

  float* x = (float*)d_out;
  float* h = (float*)d_ws;                 // 8,192,000
  float* C1 = h + 8192000;                 // 1,032,192
  float* C2 = C1 + 1032192;                // 1,032,192
  float* es = C2 + 1032192;
  float* ed = es + 64000;
  float* e1s = ed + 64000;
  float* e2s = e1s + 64000;
  float* alpha = e2s + 64000;
  float* beta = alpha + 64000;
  int* perm = (int*)(beta + 64000);
  int* kcut = perm + 64000;

  k_embed<<<1000, 256, 0, stream>>>(locs, le_W0, le_b0, le_W1, le_b1, le_bn_g,
                                    le_bn_b, le_bn_m, le_bn_v, le_Wo, le_bo,
                                    x);
  for (int l = 0; l < 3; ++l) {
    k_gemm_e<<<1000, 256, 0, stream>>>(x, gat_W + l * 128 * 128,
                                       gat_asrc + l * 128, gat_adst + l * 128,
                                       h, es, ed);
    k_sort<<<NB, 256, 0, stream>>>(es, ed, e1s, e2s, perm, kcut, alpha, beta);
    k_chunk<<<dim3(NB, 8), 128, 0, stream>>>(h, e1s, e2s, perm, C1, C2);
    k_cprefix<<<NB, 128, 0, stream>>>(C1, C2);
    if (l < 2) {
      k_out<true><<<dim3(NB, NC), 128, 0, stream>>>(
          h, C1, C2, e1s, e2s, perm, kcut, alpha, beta, gat_b + l * 128,
          bn_g + l * 128, bn_b + l * 128, bn_m + l * 128, bn_v + l * 128, x);
    } else {
      k_out<false><<<dim3(NB, NC), 128, 0, stream>>>(
          h, C1, C2, e1s, e2s, perm, kcut, alpha, beta, gat_b + 2 * 128,
          nullptr, nullptr, nullptr, nullptr, x);
    }
  }
}